// Round 2
// baseline (9638.905 us; speedup 1.0000x reference)
//
#include <hip/hip_runtime.h>
#include <math.h>

// Problem dims (fixed)
#define B_ 64
#define F_ 256
#define T_ 1024
#define H_ 1024
#define O_ 512

#define GROUPS 4
#define BLOCKS_PER_GROUP 16   // 4 waves each; wave owns 16x16 tile, K=1024

typedef short short8 __attribute__((ext_vector_type(8)));   // 8 x bf16 (4 VGPRs)
typedef float f32x4 __attribute__((ext_vector_type(4)));    // MFMA accumulator

__device__ inline float bf2f(unsigned short u) {
    union { unsigned int i; float f; } v; v.i = ((unsigned int)u) << 16; return v.f;
}
__device__ inline unsigned short f2bf(float f) {
    union { float f; unsigned int i; } v; v.f = f;
    unsigned int i = v.i;
    unsigned int r = (i + 0x7fffu + ((i >> 16) & 1u)) >> 16;  // RNE
    return (unsigned short)r;
}

// ---------------------------------------------------------------------------
// Generic fp32 (K x N) -> bf16 (N x K) tile transpose.  src[k][n] -> dst[n][k]
// grid: (N/32, K/32), block: (32, 8)
// ---------------------------------------------------------------------------
__global__ void wt_transpose(const float* __restrict__ src,
                             unsigned short* __restrict__ dst, int K, int N) {
    __shared__ float tile[32][33];
    int n0 = blockIdx.x * 32, k0 = blockIdx.y * 32;
    int tx = threadIdx.x, ty = threadIdx.y;
    for (int i = ty; i < 32; i += 8)
        tile[i][tx] = src[(size_t)(k0 + i) * N + n0 + tx];
    __syncthreads();
    for (int i = ty; i < 32; i += 8)
        dst[(size_t)(n0 + i) * K + k0 + tx] = f2bf(tile[tx][i]);
}

// ---------------------------------------------------------------------------
// x (B,F,T) fp32 -> xT (T,B,F) bf16.  grid: 64*4*16 = 4096 blocks, 256 thr
// ---------------------------------------------------------------------------
__global__ void xpose_x(const float* __restrict__ x, unsigned short* __restrict__ xT) {
    __shared__ float tile[64][65];
    int id = blockIdx.x;
    int b = id >> 6;            // 0..63
    int ft = (id >> 4) & 3;     // 0..3   (F/64)
    int tt = id & 15;           // 0..15  (T/64)
    int f0 = ft * 64, t0 = tt * 64;
    for (int i = threadIdx.x; i < 64 * 64; i += 256) {
        int fl = i >> 6, tl = i & 63;
        tile[fl][tl] = x[((size_t)(b * F_ + f0 + fl)) * T_ + t0 + tl];
    }
    __syncthreads();
    for (int i = threadIdx.x; i < 64 * 64; i += 256) {
        int tl = i >> 6, fl = i & 63;
        xT[((size_t)(t0 + tl) * B_ + b) * F_ + f0 + fl] = f2bf(tile[fl][tl]);
    }
}

// ---------------------------------------------------------------------------
// Input projection: S[r][h] = bf16( xT[r][:] @ Wx[:,h] + b[h] ),  r = t*64+b
// MFMA 16x16x32 layouts (HW-verified):
//   A frag: m = lane&15, k = (lane>>4)*8 + j      (8 contiguous bf16 -> 16B)
//   B frag: n = lane&15, k = (lane>>4)*8 + j
//   C/D   : col = lane&15, row = (lane>>4)*4 + r
// ---------------------------------------------------------------------------
__global__ __launch_bounds__(256) void proj_kernel(
    const unsigned short* __restrict__ xT, const unsigned short* __restrict__ WxT,
    const float* __restrict__ bias, unsigned short* __restrict__ S) {
    int nb = blockIdx.x;   // 0..15
    int mb = blockIdx.y;   // 0..1023
    int wave = threadIdx.x >> 6, lane = threadIdx.x & 63;
    int col16 = lane & 15, quad = lane >> 4;
    int m0 = mb * 64 + wave * 16;
    int n0 = nb * 64;

    f32x4 acc[4];
    for (int s = 0; s < 4; ++s)
        for (int r = 0; r < 4; ++r) acc[s][r] = 0.0f;

    #pragma unroll
    for (int kc = 0; kc < F_ / 32; ++kc) {
        int k0 = kc * 32 + quad * 8;
        short8 a = *reinterpret_cast<const short8*>(xT + (size_t)(m0 + col16) * F_ + k0);
        #pragma unroll
        for (int s = 0; s < 4; ++s) {
            short8 bfr = *reinterpret_cast<const short8*>(
                WxT + (size_t)(n0 + s * 16 + col16) * F_ + k0);
            acc[s] = __builtin_amdgcn_mfma_f32_16x16x32_bf16(a, bfr, acc[s], 0, 0, 0);
        }
    }
    #pragma unroll
    for (int s = 0; s < 4; ++s) {
        int col = n0 + s * 16 + col16;
        float bb = bias[col];
        #pragma unroll
        for (int r = 0; r < 4; ++r) {
            int row = m0 + quad * 4 + r;
            S[(size_t)row * H_ + col] = f2bf(acc[s][r] + bb);
        }
    }
}

// ---------------------------------------------------------------------------
// Persistent recurrence kernel — ALL 1024 steps in one dispatch.
// Batch split into 4 independent groups of 16 rows; each group = 16 blocks
// (4 waves, wave owns a 16x16 tile over K=1024). Group-internal sync via a
// monotonic per-group counter (release add / relaxed poll + acquire fence).
// Wh slice for each wave (32 B-frags = 128 VGPRs) preloaded in registers.
// S[t] holds xp_t on entry, h_t on exit (tile owned by exactly one wave).
// grid: 64 blocks x 256 threads (co-resident on 256 CUs -> no deadlock).
// ---------------------------------------------------------------------------
__global__ __launch_bounds__(256) void rnn_persistent(
    unsigned short* __restrict__ S, const unsigned short* __restrict__ WhT,
    unsigned int* __restrict__ cnt) {
    const int g  = blockIdx.x & 3;    // group: blocks of a group 8 apart -> 2 XCDs
    const int nb = blockIdx.x >> 2;   // 0..15 n-block (64 cols)
    const int wave = threadIdx.x >> 6, lane = threadIdx.x & 63;
    const int col16 = lane & 15, quad = lane >> 4;
    const int ncol = nb * 64 + wave * 16 + col16;   // this lane's B column
    const int arow = g * 16 + col16;                // this lane's A row (batch)
    const int orow = g * 16 + quad * 4;             // first output row

    // Preload Wh B-fragments for this wave's 16 columns: 32 frags = 128 VGPRs
    short8 bfr[32];
    #pragma unroll
    for (int kc = 0; kc < 32; ++kc)
        bfr[kc] = *reinterpret_cast<const short8*>(
            WhT + (size_t)ncol * H_ + kc * 32 + quad * 8);

    unsigned int* flag = cnt + g * 64;   // 256-B spaced counters

    for (int t = 0; t < T_; ++t) {
        unsigned short* St = S + (size_t)t * B_ * H_;
        if (t > 0) {
            const unsigned int target = (unsigned int)(BLOCKS_PER_GROUP * t);
            while (__hip_atomic_load(flag, __ATOMIC_RELAXED,
                                     __HIP_MEMORY_SCOPE_AGENT) < target)
                __builtin_amdgcn_s_sleep(1);
            __builtin_amdgcn_fence(__ATOMIC_ACQUIRE, "agent");
        }
        // acc = xp tile (this wave exclusively owns these 256 elements)
        f32x4 acc;
        #pragma unroll
        for (int r = 0; r < 4; ++r)
            acc[r] = bf2f(St[(size_t)(orow + r) * H_ + ncol]);

        if (t > 0) {
            const unsigned short* Sp =
                S + ((size_t)(t - 1) * B_ + arow) * H_ + quad * 8;
            #pragma unroll
            for (int kc = 0; kc < 32; ++kc) {
                short8 a = *reinterpret_cast<const short8*>(Sp + kc * 32);
                acc = __builtin_amdgcn_mfma_f32_16x16x32_bf16(a, bfr[kc], acc, 0, 0, 0);
            }
        }
        #pragma unroll
        for (int r = 0; r < 4; ++r)
            St[(size_t)(orow + r) * H_ + ncol] = f2bf(tanhf(acc[r]));

        __syncthreads();                      // drains vmcnt for all 4 waves
        if (threadIdx.x == 0) {
            __builtin_amdgcn_fence(__ATOMIC_RELEASE, "agent");
            __hip_atomic_fetch_add(flag, 1u, __ATOMIC_RELAXED,
                                   __HIP_MEMORY_SCOPE_AGENT);
        }
    }
}

// ---------------------------------------------------------------------------
// Output projection: out[b][t][o] = S[t*64+b][:] @ Wout[:,o] + bout[o]
// grid: (8, 1024); block 256 (4 waves); block tile = one t (64 b-rows) x 64 cols
// ---------------------------------------------------------------------------
__global__ __launch_bounds__(256) void out_kernel(
    const unsigned short* __restrict__ S, const unsigned short* __restrict__ WoutT,
    const float* __restrict__ bout, float* __restrict__ out) {
    int nb = blockIdx.x;   // 0..7
    int tt = blockIdx.y;   // 0..1023 (= t)
    int wave = threadIdx.x >> 6, lane = threadIdx.x & 63;
    int col16 = lane & 15, quad = lane >> 4;
    int m0 = tt * 64 + wave * 16;
    int n0 = nb * 64;

    f32x4 acc[4];
    for (int s = 0; s < 4; ++s)
        for (int r = 0; r < 4; ++r) acc[s][r] = 0.0f;

    #pragma unroll 4
    for (int kc = 0; kc < H_ / 32; ++kc) {
        int k0 = kc * 32 + quad * 8;
        short8 a = *reinterpret_cast<const short8*>(S + (size_t)(m0 + col16) * H_ + k0);
        #pragma unroll
        for (int s = 0; s < 4; ++s) {
            short8 bfr = *reinterpret_cast<const short8*>(
                WoutT + (size_t)(n0 + s * 16 + col16) * H_ + k0);
            acc[s] = __builtin_amdgcn_mfma_f32_16x16x32_bf16(a, bfr, acc[s], 0, 0, 0);
        }
    }
    #pragma unroll
    for (int s = 0; s < 4; ++s) {
        int col = n0 + s * 16 + col16;
        float bo = bout[col];
        #pragma unroll
        for (int r = 0; r < 4; ++r) {
            int bidx = wave * 16 + quad * 4 + r;   // batch index within this t
            out[((size_t)bidx * T_ + tt) * O_ + col] = acc[s][r] + bo;
        }
    }
}

// ---------------------------------------------------------------------------
extern "C" void kernel_launch(void* const* d_in, const int* in_sizes, int n_in,
                              void* d_out, int out_size, void* d_ws, size_t ws_size,
                              hipStream_t stream) {
    const float* x    = (const float*)d_in[0];   // (B,F,T)
    const float* Wx   = (const float*)d_in[1];   // (F,H)
    const float* Wh   = (const float*)d_in[2];   // (H,H)
    const float* bias = (const float*)d_in[3];   // (H)
    const float* Wout = (const float*)d_in[4];   // (H,O)
    const float* bout = (const float*)d_in[5];   // (O)
    float* out = (float*)d_out;

    // workspace layout (bf16 = ushort), total ~131.5 MB
    unsigned short* WhT   = (unsigned short*)d_ws;             // H x H   [n][k]
    unsigned short* WxT   = WhT + (size_t)H_ * H_;             // H x F   [n][k]
    unsigned short* WoutT = WxT + (size_t)H_ * F_;             // O x H   [n][k]
    unsigned short* S     = WoutT + (size_t)O_ * H_;           // T x B x H (xp -> states, in place)

    // d_out (128 MiB) doubles as scratch before out_kernel overwrites it:
    //   [0, 32 MiB)   : xT  (T x B x F bf16)
    //   [112 MiB, +1K): sync counters for the persistent kernel
    unsigned short* xT  = (unsigned short*)d_out;
    unsigned int* flags = (unsigned int*)((char*)d_out + (size_t)112 * 1024 * 1024);

    wt_transpose<<<dim3(H_ / 32, H_ / 32), dim3(32, 8), 0, stream>>>(Wh, WhT, H_, H_);
    wt_transpose<<<dim3(H_ / 32, F_ / 32), dim3(32, 8), 0, stream>>>(Wx, WxT, F_, H_);
    wt_transpose<<<dim3(O_ / 32, H_ / 32), dim3(32, 8), 0, stream>>>(Wout, WoutT, H_, O_);
    xpose_x<<<dim3(4096), dim3(256), 0, stream>>>(x, xT);

    proj_kernel<<<dim3(16, 1024), dim3(256), 0, stream>>>(xT, WxT, bias, S);

    hipMemsetAsync(flags, 0, GROUPS * 64 * sizeof(unsigned int), stream);
    rnn_persistent<<<dim3(GROUPS * BLOCKS_PER_GROUP), dim3(256), 0, stream>>>(
        S, WhT, flags);

    out_kernel<<<dim3(8, 1024), dim3(256), 0, stream>>>(S, WoutT, bout, out);
}